// Round 10
// baseline (987.560 us; speedup 1.0000x reference)
//
#include <hip/hip_runtime.h>
#include <cstdint>

typedef _Float16 f16_t;
typedef __attribute__((ext_vector_type(8))) _Float16 f16x8;
typedef __attribute__((ext_vector_type(4))) _Float16 f16x4;
typedef __attribute__((ext_vector_type(2))) _Float16 f16x2;
typedef __attribute__((ext_vector_type(4))) float f32x4;

#define HP      160      // padded H (150 -> 160): h/c row stride, U K-dim
#define NCOL    640      // 160 j x 4 gates (P is [v][j][g] interleaved)
#define KXP     320      // padded X_SIZE (300 -> 320)
#define NNODES  524287
#define LEAF_S  262143
#define LEAF_M  262144
#define NVOCAB  50000
#define AST     168      // A_sh stride (f16): 16B-aligned, 2-way-bank-free

__device__ __forceinline__ float frcp(float x) { return __builtin_amdgcn_rcpf(x); }
__device__ __forceinline__ float sigf(float x) { return frcp(1.0f + __expf(-x)); }
__device__ __forceinline__ float tanhf_(float x) {
  return 1.0f - 2.0f * frcp(1.0f + __expf(2.0f * x));
}
__device__ __forceinline__ f16x8 zero8() {
  f16x8 z;
#pragma unroll
  for (int i = 0; i < 8; ++i) z[i] = (_Float16)0.0f;
  return z;
}
__device__ __forceinline__ f32x4 zero4() {
  f32x4 z;
#pragma unroll
  for (int i = 0; i < 4; ++i) z[i] = 0.0f;
  return z;
}

// WreT[colIdx][k], colIdx = j*4+g (interleaved, matches P);
// UreT[col][k], col = g*160+j (g-major, matches B staging); bre interleaved.
__global__ void prep_params(const float* __restrict__ W_iou, const float* __restrict__ U_iou,
                            const float* __restrict__ b_iou, const float* __restrict__ W_f,
                            const float* __restrict__ U_f, const float* __restrict__ b_f,
                            f16_t* __restrict__ WreT, f16_t* __restrict__ UreT,
                            float* __restrict__ bre) {
  int idx = blockIdx.x * 256 + threadIdx.x;
  if (idx < NCOL * KXP) {
    int col = idx / KXP, k = idx % KXP;
    int j = col >> 2, g = col & 3;
    float v = 0.0f;
    if (k < 300 && j < 150) v = (g < 3) ? W_iou[k * 450 + g * 150 + j] : W_f[k * 150 + j];
    WreT[idx] = (f16_t)v;
  } else if (idx < NCOL * KXP + NCOL * HP) {
    int i2 = idx - NCOL * KXP;
    int col = i2 / HP, k = i2 % HP;
    int g = col / 160, j = col % 160;
    float v = 0.0f;
    if (k < 150 && j < 150) v = (g < 3) ? U_iou[k * 450 + g * 150 + j] : U_f[k * 150 + j];
    UreT[i2] = (f16_t)v;
  } else if (idx < NCOL * KXP + NCOL * HP + NCOL) {
    int col = idx - (NCOL * KXP + NCOL * HP);
    int j = col >> 2, g = col & 3;
    bre[col] = (j < 150) ? ((g < 3) ? b_iou[g * 150 + j] : b_f[j]) : 0.0f;
  }
}

// P[v][j][g] = emb @ W + b, fp16, 50000 x 640 (interleaved cols).
__global__ __launch_bounds__(256) void gemm_p(const float* __restrict__ emb,
                                              const f16_t* __restrict__ WreT,
                                              const float* __restrict__ bre,
                                              f16_t* __restrict__ P) {
  __shared__ __align__(16) f16_t A_sh[64 * 328];
  __shared__ __align__(16) f16_t B_sh[128 * 40];
  const int tid = threadIdx.x;
  const int wid = tid >> 6, lane = tid & 63, l15 = lane & 15, q = lane >> 4;
  const int row0 = blockIdx.x * 64;

#pragma unroll
  for (int i = 0; i < 10; ++i) {
    int ch = tid + 256 * i;
    int r = ch / 40, kc = (ch % 40) * 8;
    int grow = row0 + r;
    f16x8 hv;
    if (grow < NVOCAB && kc + 8 <= 300) {
      float4 a = *(const float4*)&emb[grow * 300 + kc];
      float4 b = *(const float4*)&emb[grow * 300 + kc + 4];
      hv[0] = (_Float16)a.x; hv[1] = (_Float16)a.y; hv[2] = (_Float16)a.z; hv[3] = (_Float16)a.w;
      hv[4] = (_Float16)b.x; hv[5] = (_Float16)b.y; hv[6] = (_Float16)b.z; hv[7] = (_Float16)b.w;
    } else {
#pragma unroll
      for (int e = 0; e < 8; ++e) {
        int k = kc + e;
        float v = (grow < NVOCAB && k < 300) ? emb[grow * 300 + k] : 0.0f;
        hv[e] = (_Float16)v;
      }
    }
    *(f16x8*)&A_sh[r * 328 + kc] = hv;
  }
  __syncthreads();

  for (int bn = 0; bn < 5; ++bn) {
    const int col0 = bn * 128;
    f32x4 acc[8];
#pragma unroll
    for (int t = 0; t < 8; ++t) acc[t] = zero4();
    for (int kk = 0; kk < KXP; kk += 32) {
#pragma unroll
      for (int i = 0; i < 2; ++i) {
        int ch = tid + 256 * i;
        int cidx = ch >> 2, kc = (ch & 3) * 8;
        *(f16x8*)&B_sh[cidx * 40 + kc] =
            *(const f16x8*)&WreT[(col0 + cidx) * KXP + kk + kc];
      }
      __syncthreads();
      f16x8 af = *(const f16x8*)&A_sh[(16 * wid + l15) * 328 + kk + q * 8];
#pragma unroll
      for (int t = 0; t < 8; ++t) {
        f16x8 bfr = *(const f16x8*)&B_sh[(t * 16 + l15) * 40 + q * 8];
        acc[t] = __builtin_amdgcn_mfma_f32_16x16x32_f16(af, bfr, acc[t], 0, 0, 0);
      }
      __syncthreads();
    }
#pragma unroll
    for (int t = 0; t < 8; ++t) {
      int col = col0 + t * 16 + l15;
      float bias = bre[col];
#pragma unroll
      for (int r2 = 0; r2 < 4; ++r2) {
        int row = row0 + 16 * wid + q * 4 + r2;
        if (row < NVOCAB) P[(long)row * NCOL + col] = (f16_t)(acc[t][r2] + bias);
      }
    }
  }
}

// Merged leaf kernel: per vocab row, compute Hleaf/Cleaf AND Oleaf in one
// pass over P (replaces leafhc + oleaf: one launch, no P re-read).
// 16 lanes per row, 16 rows per block, grid 3125 (= 50000 rows exact).
__global__ void leafhco_kernel(const f16_t* __restrict__ P, const float* __restrict__ W_out,
                               const float* __restrict__ b_out, f16_t* __restrict__ Hleaf,
                               f16_t* __restrict__ Cleaf, float* __restrict__ Oleaf) {
  const int tid = threadIdx.x;
  const int row = blockIdx.x * 16 + (tid >> 4), l = tid & 15;
  const f16_t* Pr = P + (long)row * NCOL;
  float oacc[5] = {0, 0, 0, 0, 0};
#pragma unroll
  for (int jj = 0; jj < 10; ++jj) {
    int j = jj * 16 + l;
    f16x4 pp = *(const f16x4*)&Pr[j * 4];
    float iv = (float)pp[0], ov = (float)pp[1], uv = (float)pp[2];
    float cl = sigf(iv) * tanhf_(uv);     // pads (j>=150): P cols exactly 0 -> cl=hl=0
    float hl = sigf(ov) * tanhf_(cl);
    Hleaf[(long)row * HP + j] = (f16_t)hl;
    Cleaf[(long)row * HP + j] = (f16_t)cl;
    int wbase = (j < 150) ? j * 5 : 0;    // hl==0 on pads
#pragma unroll
    for (int m = 0; m < 5; ++m) oacc[m] += hl * W_out[wbase + m];
  }
#pragma unroll
  for (int m = 0; m < 5; ++m) {
    float vv = oacc[m];
    vv += __shfl_xor(vv, 1);
    vv += __shfl_xor(vv, 2);
    vv += __shfl_xor(vv, 4);
    vv += __shfl_xor(vv, 8);
    if (l == 0) Oleaf[(long)row * 8 + m] = vv + b_out[m];
  }
}

// LEVEL 17, big-M tile: 128 leaves -> 64 parents per block (2048 blocks).
// Also writes the LEAF output rows (its 128 leaves) from Oleaf — the old
// leafout kernel folded in (saves a launch).
__global__ __launch_bounds__(256, 3) void level17b_kernel(
    const int* __restrict__ x_id, const f16_t* __restrict__ P,
    const f16_t* __restrict__ UreT, const f16_t* __restrict__ Hleaf,
    const f16_t* __restrict__ Cleaf, const float* __restrict__ Oleaf,
    f16_t* __restrict__ Hout, f16_t* __restrict__ Cout,
    const float* __restrict__ W_out, const float* __restrict__ b_out,
    float* __restrict__ out) {
  __shared__ __align__(16) f16_t A_sh[128 * AST];
  __shared__ __align__(16) f16_t B_sh[128 * 40];
  const int tid = threadIdx.x;
  const int wid = tid >> 6, lane = tid & 63, l15 = lane & 15, q = lane >> 4;
  const int p0 = blockIdx.x * 64;
  const int s1 = (1 << 17) - 1;                  // 131071
  const long childbase = 2L * s1 + 1 + 2 * p0;   // first child (leaf) node id

#pragma unroll
  for (int i = 0; i < 10; ++i) {
    int ch = tid + 256 * i;
    int r = ch / 20, kc = (ch % 20) * 8;
    int xv = x_id[childbase + r];
    *(f16x8*)&A_sh[r * AST + kc] = *(const f16x8*)&Hleaf[(long)xv * HP + kc];
  }
  __syncthreads();

  int xvp[2][2], xvl[2][2], xvr[2][2];
#pragma unroll
  for (int mt = 0; mt < 2; ++mt)
#pragma unroll
    for (int rr = 0; rr < 2; ++rr) {
      int pl = 16 * wid + 8 * mt + 2 * q + rr;   // 0..63
      xvp[mt][rr] = x_id[(long)s1 + p0 + pl];
      xvl[mt][rr] = x_id[childbase + 2 * pl];
      xvr[mt][rr] = x_id[childbase + 2 * pl + 1];
    }
  float oacc[2][2][5] = {};

  for (int jt = 0; jt < 5; ++jt) {
    const int j0 = jt * 32;
    f32x4 acc[2][4][2];
#pragma unroll
    for (int mt = 0; mt < 2; ++mt)
#pragma unroll
      for (int g = 0; g < 4; ++g)
#pragma unroll
        for (int jh = 0; jh < 2; ++jh) acc[mt][g][jh] = zero4();

    for (int kk = 0; kk < HP; kk += 32) {
#pragma unroll
      for (int i = 0; i < 2; ++i) {
        int ch = tid + 256 * i;
        int cidx = ch >> 2, kc = (ch & 3) * 8;
        int g = cidx >> 5, jj = cidx & 31;
        int col = g * HP + j0 + jj;
        *(f16x8*)&B_sh[cidx * 40 + kc] = *(const f16x8*)&UreT[col * HP + kk + kc];
      }
      __syncthreads();
      f16x8 af0 = *(const f16x8*)&A_sh[(32 * wid + l15) * AST + kk + q * 8];
      f16x8 af1 = *(const f16x8*)&A_sh[(32 * wid + 16 + l15) * AST + kk + q * 8];
#pragma unroll
      for (int g = 0; g < 4; ++g)
#pragma unroll
        for (int jh = 0; jh < 2; ++jh) {
          f16x8 bfr = *(const f16x8*)&B_sh[(g * 32 + jh * 16 + l15) * 40 + q * 8];
          acc[0][g][jh] = __builtin_amdgcn_mfma_f32_16x16x32_f16(af0, bfr, acc[0][g][jh], 0, 0, 0);
          acc[1][g][jh] = __builtin_amdgcn_mfma_f32_16x16x32_f16(af1, bfr, acc[1][g][jh], 0, 0, 0);
        }
      __syncthreads();
    }

#pragma unroll
    for (int mt = 0; mt < 2; ++mt)
#pragma unroll
      for (int rr = 0; rr < 2; ++rr) {
        const int r = rr * 2;
        const int pl = 16 * wid + 8 * mt + 2 * q + rr;  // local parent 0..63
        const f16_t* Prp = P + (long)xvp[mt][rr] * NCOL;
#pragma unroll
        for (int jh = 0; jh < 2; ++jh) {
          const int j = j0 + jh * 16 + l15;
          f16x4 pp = *(const f16x4*)&Prp[j * 4];
          float ipre = (float)pp[0] + acc[mt][0][jh][r] + acc[mt][0][jh][r + 1];
          float opre = (float)pp[1] + acc[mt][1][jh][r] + acc[mt][1][jh][r + 1];
          float upre = (float)pp[2] + acc[mt][2][jh][r] + acc[mt][2][jh][r + 1];
          float pf   = (float)pp[3];
          float fl = sigf(pf + acc[mt][3][jh][r]);
          float fr = sigf(pf + acc[mt][3][jh][r + 1]);
          float clv = (float)Cleaf[(long)xvl[mt][rr] * HP + j];
          float crv = (float)Cleaf[(long)xvr[mt][rr] * HP + j];
          float cn = sigf(ipre) * tanhf_(upre) + fl * clv + fr * crv;
          float hn = sigf(opre) * tanhf_(cn);
          Hout[(long)(p0 + pl) * HP + j] = (f16_t)hn;   // pads stay exactly 0
          Cout[(long)(p0 + pl) * HP + j] = (f16_t)cn;
          int wbase = (j < 150) ? j * 5 : 0;            // hn==0 on pads
#pragma unroll
          for (int m = 0; m < 5; ++m) oacc[mt][rr][m] += hn * W_out[wbase + m];
        }
      }
  }

#pragma unroll
  for (int mt = 0; mt < 2; ++mt)
#pragma unroll
    for (int rr = 0; rr < 2; ++rr) {
      int pl = 16 * wid + 8 * mt + 2 * q + rr;
#pragma unroll
      for (int m = 0; m < 5; ++m) {
        float v = oacc[mt][rr][m];
        v += __shfl_xor(v, 1);
        v += __shfl_xor(v, 2);
        v += __shfl_xor(v, 4);
        v += __shfl_xor(v, 8);
        if (l15 == 0) out[((long)s1 + p0 + pl) * 5 + m] = v + b_out[m];
      }
    }

  // ---- folded leafout: this block's 128 leaves ----
  if (tid < 128) {
    long leaf = childbase + tid;
    int xv = x_id[leaf];
    const float* O = Oleaf + (long)xv * 8;
    float4 o4 = *(const float4*)O;
    float o5 = O[4];
    long base = leaf * 5;
    out[base + 0] = o4.x; out[base + 1] = o4.y; out[base + 2] = o4.z;
    out[base + 3] = o4.w; out[base + 4] = o5;
  }
}

// Big-M fused pair: 128 children -> 64 parents (pass 1, h/c carried in
// packed f16x2 registers) -> 32 grandparents (pass 2, FULL 4-wave).
// After pass 1, A_sh is dead: parent h -> rows 0..63, parent c -> rows
// 64..127. LDS = 53.2 KB -> 3 blocks/CU. Grids are exact (M1 = 64*grid).
__global__ __launch_bounds__(256, 3) void fusedb_kernel(
    const int* __restrict__ x_id, const f16_t* __restrict__ P,
    const f16_t* __restrict__ UreT, const f16_t* __restrict__ Hc,
    const f16_t* __restrict__ Cc, f16_t* __restrict__ Hout,
    f16_t* __restrict__ Cout, const float* __restrict__ W_out,
    const float* __restrict__ b_out, float* __restrict__ out, int s1) {
  __shared__ __align__(16) f16_t A_sh[128 * AST];
  __shared__ __align__(16) f16_t B_sh[128 * 40];
  const int tid = threadIdx.x;
  const int wid = tid >> 6, lane = tid & 63, l15 = lane & 15, q = lane >> 4;
  const int p0 = blockIdx.x * 64;

  // ---- stage A: 128 child h rows ----
#pragma unroll
  for (int i = 0; i < 10; ++i) {
    int ch = tid + 256 * i;
    int r = ch / 20, kc = (ch % 20) * 8;
    *(f16x8*)&A_sh[r * AST + kc] = *(const f16x8*)&Hc[(long)(2 * p0 + r) * HP + kc];
  }
  __syncthreads();

  // ---- pass 1: 64 parents, h/c held in packed f16 registers ----
  int xvp[2][2];
#pragma unroll
  for (int mt = 0; mt < 2; ++mt)
#pragma unroll
    for (int rr = 0; rr < 2; ++rr) {
      int pl = 16 * wid + 8 * mt + 2 * q + rr;   // 0..63
      xvp[mt][rr] = x_id[(long)s1 + p0 + pl];
    }
  f16x2 hreg[5][2][2];   // [jt][mt][rr], lanes = jh
  f16x2 creg[5][2][2];

#pragma unroll
  for (int jt = 0; jt < 5; ++jt) {
    const int j0 = jt * 32;
    f32x4 acc[2][4][2];
#pragma unroll
    for (int mt = 0; mt < 2; ++mt)
#pragma unroll
      for (int g = 0; g < 4; ++g)
#pragma unroll
        for (int jh = 0; jh < 2; ++jh) acc[mt][g][jh] = zero4();

    for (int kk = 0; kk < HP; kk += 32) {
#pragma unroll
      for (int i = 0; i < 2; ++i) {
        int ch = tid + 256 * i;
        int cidx = ch >> 2, kc = (ch & 3) * 8;
        int g = cidx >> 5, jj = cidx & 31;
        int col = g * HP + j0 + jj;
        *(f16x8*)&B_sh[cidx * 40 + kc] = *(const f16x8*)&UreT[col * HP + kk + kc];
      }
      __syncthreads();
      f16x8 af0 = *(const f16x8*)&A_sh[(32 * wid + l15) * AST + kk + q * 8];
      f16x8 af1 = *(const f16x8*)&A_sh[(32 * wid + 16 + l15) * AST + kk + q * 8];
#pragma unroll
      for (int g = 0; g < 4; ++g)
#pragma unroll
        for (int jh = 0; jh < 2; ++jh) {
          f16x8 bfr = *(const f16x8*)&B_sh[(g * 32 + jh * 16 + l15) * 40 + q * 8];
          acc[0][g][jh] = __builtin_amdgcn_mfma_f32_16x16x32_f16(af0, bfr, acc[0][g][jh], 0, 0, 0);
          acc[1][g][jh] = __builtin_amdgcn_mfma_f32_16x16x32_f16(af1, bfr, acc[1][g][jh], 0, 0, 0);
        }
      __syncthreads();
    }

#pragma unroll
    for (int mt = 0; mt < 2; ++mt)
#pragma unroll
      for (int rr = 0; rr < 2; ++rr) {
        const int r = rr * 2;
        const int lr0 = 32 * wid + 16 * mt + 4 * q + r;  // even child row 0..127
        const f16_t* Prp = P + (long)xvp[mt][rr] * NCOL;
#pragma unroll
        for (int jh = 0; jh < 2; ++jh) {
          const int j = j0 + jh * 16 + l15;
          f16x4 pp = *(const f16x4*)&Prp[j * 4];
          float ipre = (float)pp[0] + acc[mt][0][jh][r] + acc[mt][0][jh][r + 1];
          float opre = (float)pp[1] + acc[mt][1][jh][r] + acc[mt][1][jh][r + 1];
          float upre = (float)pp[2] + acc[mt][2][jh][r] + acc[mt][2][jh][r + 1];
          float pf   = (float)pp[3];
          float fl = sigf(pf + acc[mt][3][jh][r]);
          float fr = sigf(pf + acc[mt][3][jh][r + 1]);
          float clv = (float)Cc[(long)(2 * p0 + lr0) * HP + j];
          float crv = (float)Cc[(long)(2 * p0 + lr0 + 1) * HP + j];
          float cn = sigf(ipre) * tanhf_(upre) + fl * clv + fr * crv;
          float hn = sigf(opre) * tanhf_(cn);
          hreg[jt][mt][rr][jh] = (_Float16)hn;
          creg[jt][mt][rr][jh] = (_Float16)cn;
        }
      }
  }

  // A_sh is dead (last pass-1 kk barrier passed): parent h -> rows 0..63,
  // parent c -> rows 64..127. Pass-2's first stage-B barrier orders these
  // writes before any pass-2 read.
#pragma unroll
  for (int jt = 0; jt < 5; ++jt)
#pragma unroll
    for (int mt = 0; mt < 2; ++mt)
#pragma unroll
      for (int rr = 0; rr < 2; ++rr) {
        const int pl = 16 * wid + 8 * mt + 2 * q + rr;
#pragma unroll
        for (int jh = 0; jh < 2; ++jh) {
          const int j = jt * 32 + jh * 16 + l15;
          A_sh[pl * AST + j] = hreg[jt][mt][rr][jh];
          A_sh[(64 + pl) * AST + j] = creg[jt][mt][rr][jh];
        }
      }

  // pass-1 out rows (computed from hreg after the jt loop to keep the
  // loop-live register set small)
  {
    float oacc1[2][2][5] = {};
#pragma unroll
    for (int jt = 0; jt < 5; ++jt)
#pragma unroll
      for (int mt = 0; mt < 2; ++mt)
#pragma unroll
        for (int rr = 0; rr < 2; ++rr)
#pragma unroll
          for (int jh = 0; jh < 2; ++jh) {
            const int j = jt * 32 + jh * 16 + l15;
            float hn = (float)hreg[jt][mt][rr][jh];
            int wbase = (j < 150) ? j * 5 : 0;
#pragma unroll
            for (int m = 0; m < 5; ++m) oacc1[mt][rr][m] += hn * W_out[wbase + m];
          }
#pragma unroll
    for (int mt = 0; mt < 2; ++mt)
#pragma unroll
      for (int rr = 0; rr < 2; ++rr) {
        int pl = 16 * wid + 8 * mt + 2 * q + rr;
#pragma unroll
        for (int m = 0; m < 5; ++m) {
          float v = oacc1[mt][rr][m];
          v += __shfl_xor(v, 1);
          v += __shfl_xor(v, 2);
          v += __shfl_xor(v, 4);
          v += __shfl_xor(v, 8);
          if (l15 == 0) out[((long)s1 + p0 + pl) * 5 + m] = v + b_out[m];
        }
      }
  }

  // ---- pass 2: 64 parents -> 32 grandparents, FULL 4-wave ----
  const int s2 = (s1 - 1) >> 1;
  const int p02 = p0 >> 1;
  int xvp2[2];
#pragma unroll
  for (int rr = 0; rr < 2; ++rr) {
    int pl2 = 8 * wid + 2 * q + rr;              // 0..31
    xvp2[rr] = x_id[(long)s2 + p02 + pl2];
  }
  float oacc2[2][5] = {};

  for (int jt = 0; jt < 5; ++jt) {
    const int j0 = jt * 32;
    f32x4 acc[4][2];
#pragma unroll
    for (int g = 0; g < 4; ++g)
#pragma unroll
      for (int jh = 0; jh < 2; ++jh) acc[g][jh] = zero4();

    for (int kk = 0; kk < HP; kk += 32) {
#pragma unroll
      for (int i = 0; i < 2; ++i) {
        int ch = tid + 256 * i;
        int cidx = ch >> 2, kc = (ch & 3) * 8;
        int g = cidx >> 5, jj = cidx & 31;
        int col = g * HP + j0 + jj;
        *(f16x8*)&B_sh[cidx * 40 + kc] = *(const f16x8*)&UreT[col * HP + kk + kc];
      }
      __syncthreads();   // orders pass-1 A_sh parent writes before reads too
      f16x8 af = *(const f16x8*)&A_sh[(16 * wid + l15) * AST + kk + q * 8];
#pragma unroll
      for (int g = 0; g < 4; ++g)
#pragma unroll
        for (int jh = 0; jh < 2; ++jh) {
          f16x8 bfr = *(const f16x8*)&B_sh[(g * 32 + jh * 16 + l15) * 40 + q * 8];
          acc[g][jh] = __builtin_amdgcn_mfma_f32_16x16x32_f16(af, bfr, acc[g][jh], 0, 0, 0);
        }
      __syncthreads();
    }

#pragma unroll
    for (int rr = 0; rr < 2; ++rr) {
      const int r = rr * 2;
      const int lr0 = 16 * wid + 4 * q + r;      // even parent row 0..63
      const int pl2 = lr0 >> 1;                  // 0..31
      const f16_t* Prp = P + (long)xvp2[rr] * NCOL;
#pragma unroll
      for (int jh = 0; jh < 2; ++jh) {
        const int j = j0 + jh * 16 + l15;
        f16x4 pp = *(const f16x4*)&Prp[j * 4];
        float ipre = (float)pp[0] + acc[0][jh][r] + acc[0][jh][r + 1];
        float opre = (float)pp[1] + acc[1][jh][r] + acc[1][jh][r + 1];
        float upre = (float)pp[2] + acc[2][jh][r] + acc[2][jh][r + 1];
        float pf   = (float)pp[3];
        float fl = sigf(pf + acc[3][jh][r]);
        float fr = sigf(pf + acc[3][jh][r + 1]);
        float clv = (float)A_sh[(64 + lr0) * AST + j];       // parent c
        float crv = (float)A_sh[(64 + lr0 + 1) * AST + j];
        float cn = sigf(ipre) * tanhf_(upre) + fl * clv + fr * crv;
        float hn = sigf(opre) * tanhf_(cn);
        Hout[(long)(p02 + pl2) * HP + j] = (f16_t)hn;
        Cout[(long)(p02 + pl2) * HP + j] = (f16_t)cn;
        int wbase = (j < 150) ? j * 5 : 0;
#pragma unroll
        for (int m = 0; m < 5; ++m) oacc2[rr][m] += hn * W_out[wbase + m];
      }
    }
  }

#pragma unroll
  for (int rr = 0; rr < 2; ++rr) {
    int pl2 = 8 * wid + 2 * q + rr;
#pragma unroll
    for (int m = 0; m < 5; ++m) {
      float v = oacc2[rr][m];
      v += __shfl_xor(v, 1);
      v += __shfl_xor(v, 2);
      v += __shfl_xor(v, 4);
      v += __shfl_xor(v, 8);
      if (l15 == 0) out[((long)s2 + p02 + pl2) * 5 + m] = v + b_out[m];
    }
  }
}

// ---------------- single-level tile for the tail (unchanged, proven) -------
__device__ __forceinline__ void level_tile(
    const int* __restrict__ x_id, const f16_t* __restrict__ P,
    const f16_t* __restrict__ UreT, const f16_t* __restrict__ h_child,
    const f16_t* __restrict__ c_child, f16_t* __restrict__ h_par,
    f16_t* __restrict__ c_par, const float* Wo, const float* __restrict__ b_out,
    float* __restrict__ out, int s, int M, int p0, f16_t* A_sh, f16_t* B_sh) {
  const int tid = threadIdx.x;
  const int wid = tid >> 6, lane = tid & 63, l15 = lane & 15, q = lane >> 4;
  int rowsValid = 2 * M - 2 * p0;
  if (rowsValid > 64) rowsValid = 64;

#pragma unroll
  for (int i = 0; i < 5; ++i) {
    int ch = tid + 256 * i;
    int r = ch / 20, kc = (ch % 20) * 8;
    f16x8 v;
    if (r < rowsValid) v = *(const f16x8*)&h_child[(long)(2 * p0 + r) * HP + kc];
    else v = zero8();
    *(f16x8*)&A_sh[r * 184 + kc] = v;
  }
  __syncthreads();

  int xvp[2]; long pnode[2]; int plg[2]; bool valid[2]; int lr0v[2];
#pragma unroll
  for (int rr = 0; rr < 2; ++rr) {
    int lr0 = 16 * wid + q * 4 + rr * 2;
    int pl = lr0 >> 1;
    valid[rr] = (p0 + pl) < M;
    long pn = (long)s + p0 + (valid[rr] ? pl : 0);
    pnode[rr] = pn; plg[rr] = p0 + pl; lr0v[rr] = lr0;
    xvp[rr] = x_id[pn];
  }

  float oacc[2][5];
#pragma unroll
  for (int rr = 0; rr < 2; ++rr)
#pragma unroll
    for (int m = 0; m < 5; ++m) oacc[rr][m] = 0.0f;

  for (int jt = 0; jt < 5; ++jt) {
    const int j0 = jt * 32;
    f32x4 acc[4][2];
#pragma unroll
    for (int g = 0; g < 4; ++g)
#pragma unroll
      for (int jh = 0; jh < 2; ++jh) acc[g][jh] = zero4();

    for (int kk = 0; kk < HP; kk += 32) {
#pragma unroll
      for (int i = 0; i < 2; ++i) {
        int ch = tid + 256 * i;
        int cidx = ch >> 2, kc = (ch & 3) * 8;
        int g = cidx >> 5, jj = cidx & 31;
        int col = g * HP + j0 + jj;
        *(f16x8*)&B_sh[cidx * 40 + kc] = *(const f16x8*)&UreT[col * HP + kk + kc];
      }
      __syncthreads();
      f16x8 af = *(const f16x8*)&A_sh[(16 * wid + l15) * 184 + kk + q * 8];
#pragma unroll
      for (int g = 0; g < 4; ++g)
#pragma unroll
        for (int jh = 0; jh < 2; ++jh) {
          f16x8 bfr = *(const f16x8*)&B_sh[(g * 32 + jh * 16 + l15) * 40 + q * 8];
          acc[g][jh] = __builtin_amdgcn_mfma_f32_16x16x32_f16(af, bfr, acc[g][jh], 0, 0, 0);
        }
      __syncthreads();
    }

#pragma unroll
    for (int rr = 0; rr < 2; ++rr) {
      const int r = rr * 2;
      const f16_t* Prp = P + (long)xvp[rr] * NCOL;
#pragma unroll
      for (int jh = 0; jh < 2; ++jh) {
        const int j = j0 + jh * 16 + l15;
        f16x4 pp = *(const f16x4*)&Prp[j * 4];
        float ipre = (float)pp[0] + acc[0][jh][r] + acc[0][jh][r + 1];
        float opre = (float)pp[1] + acc[1][jh][r] + acc[1][jh][r + 1];
        float upre = (float)pp[2] + acc[2][jh][r] + acc[2][jh][r + 1];
        float pf   = (float)pp[3];
        float fl = sigf(pf + acc[3][jh][r]);
        float fr = sigf(pf + acc[3][jh][r + 1]);
        float clv = valid[rr] ? (float)c_child[(long)(2 * p0 + lr0v[rr]) * HP + j] : 0.0f;
        float crv = valid[rr] ? (float)c_child[(long)(2 * p0 + lr0v[rr] + 1) * HP + j] : 0.0f;
        float cn = sigf(ipre) * tanhf_(upre) + fl * clv + fr * crv;
        float hn = sigf(opre) * tanhf_(cn);
        if (valid[rr]) {
          h_par[(long)plg[rr] * HP + j] = (f16_t)hn;
          c_par[(long)plg[rr] * HP + j] = (f16_t)cn;
        }
#pragma unroll
        for (int m = 0; m < 5; ++m) oacc[rr][m] += hn * Wo[j * 5 + m];
      }
    }
  }

#pragma unroll
  for (int rr = 0; rr < 2; ++rr) {
#pragma unroll
    for (int m = 0; m < 5; ++m) {
      float v = oacc[rr][m];
      v += __shfl_xor(v, 1);
      v += __shfl_xor(v, 2);
      v += __shfl_xor(v, 4);
      v += __shfl_xor(v, 8);
      if (l15 == 0 && valid[rr]) out[pnode[rr] * 5 + m] = v + b_out[m];
    }
  }
}

// Levels 4..0 (children: L5 in HA/CA): one block, barriers between levels.
__global__ __launch_bounds__(256, 4) void tail_kernel(
    const int* __restrict__ x_id, const f16_t* __restrict__ P,
    const f16_t* __restrict__ UreT, f16_t* __restrict__ HA, f16_t* __restrict__ HB,
    f16_t* __restrict__ CA, f16_t* __restrict__ CB, const float* __restrict__ W_out,
    const float* __restrict__ b_out, float* __restrict__ out) {
  __shared__ __align__(16) f16_t A_sh[64 * 184];
  __shared__ __align__(16) f16_t B_sh[128 * 40];
  __shared__ float Wo[800];
  for (int i = threadIdx.x; i < 800; i += 256) Wo[i] = (i < 750) ? W_out[i] : 0.0f;
  for (int lvl = 4; lvl >= 0; --lvl) {
    int s = (1 << lvl) - 1, M = 1 << lvl;
    const f16_t* hc = ((lvl + 1) & 1) ? HA : HB;
    const f16_t* cc = ((lvl + 1) & 1) ? CA : CB;
    f16_t* hp = (lvl & 1) ? HA : HB;
    f16_t* cp = (lvl & 1) ? CA : CB;
    level_tile(x_id, P, UreT, hc, cc, hp, cp, Wo, b_out, out, s, M, 0, A_sh, B_sh);
    __syncthreads();
  }
}

extern "C" void kernel_launch(void* const* d_in, const int* in_sizes, int n_in,
                              void* d_out, int out_size, void* d_ws, size_t ws_size,
                              hipStream_t stream) {
  const int* x_id   = (const int*)d_in[0];
  const float* emb  = (const float*)d_in[1];
  const float* W_iou = (const float*)d_in[2];
  const float* U_iou = (const float*)d_in[3];
  const float* b_iou = (const float*)d_in[4];
  const float* W_f   = (const float*)d_in[5];
  const float* U_f   = (const float*)d_in[6];
  const float* b_f   = (const float*)d_in[7];
  const float* W_out = (const float*)d_in[8];
  const float* b_out = (const float*)d_in[9];
  float* out = (float*)d_out;
  char* ws = (char*)d_ws;

  // workspace carve (bytes), peak 182,103,040 == budget (Oleaf exact fit).
  // All region reuses are stream-ordered (writer launched after last reader).
  f16_t* WreT  = (f16_t*)(ws + 0);              // 409,600
  f16_t* UreT  = (f16_t*)(ws + 409600);         // 204,800
  float* bre   = (float*)(ws + 614400);         // 2,560
  f16_t* P     = (f16_t*)(ws + 616960);         // 64,000,000 (persistent)
  f16_t* Hleaf = (f16_t*)(ws + 64616960);       // 16,000,000 (dead after L17)
  f16_t* Cleaf = (f16_t*)(ws + 80616960);       // 16,000,000 (dead after L17)
  f16_t* H17   = (f16_t*)(ws + 96616960);       // 41,943,040 (131072 rows)
  f16_t* C17   = (f16_t*)(ws + 138560000);      // 41,943,040 -> ends 180,503,040
  float* Oleaf = (float*)(ws + 180503040);      // 1,600,000 -> ends 182,103,040
  f16_t* H15 = (f16_t*)(ws + 64616960);         // 10,485,760 (32768 rows) over Hleaf
  f16_t* C15 = (f16_t*)(ws + 75102720);         // 10,485,760
  f16_t* H13 = (f16_t*)(ws + 96616960);         //  2,621,440 (8192 rows) over H17
  f16_t* C13 = (f16_t*)(ws + 99238400);         //  2,621,440
  f16_t* H11 = (f16_t*)(ws + 64616960);         //    655,360 (2048 rows) over H15
  f16_t* C11 = (f16_t*)(ws + 65272320);         //    655,360
  f16_t* H9  = (f16_t*)(ws + 96616960);         //    163,840 (512 rows) over H13
  f16_t* C9  = (f16_t*)(ws + 96780800);         //    163,840
  f16_t* H7  = (f16_t*)(ws + 64616960);         //     40,960 (128 rows) over H11
  f16_t* C7  = (f16_t*)(ws + 64657920);         //     40,960
  f16_t* H5  = (f16_t*)(ws + 96616960);         //     10,240 (32 rows) over H9
  f16_t* C5  = (f16_t*)(ws + 96627200);         //     10,240
  f16_t* HSc = (f16_t*)(ws + 64616960);         // tail scratch (over H7, dead)
  f16_t* CSc = (f16_t*)(ws + 64627200);         // tail scratch

  prep_params<<<1203, 256, 0, stream>>>(W_iou, U_iou, b_iou, W_f, U_f, b_f, WreT, UreT, bre);
  gemm_p<<<782, 256, 0, stream>>>(emb, WreT, bre, P);
  leafhco_kernel<<<3125, 256, 0, stream>>>(P, W_out, b_out, Hleaf, Cleaf, Oleaf);

  // level 17: big-M tile + folded leaf-output gather
  level17b_kernel<<<2048, 256, 0, stream>>>(x_id, P, UreT, Hleaf, Cleaf, Oleaf,
                                            H17, C17, W_out, b_out, out);
  // big-M fused pairs (128 children -> 64 -> 32 per block, exact grids):
  fusedb_kernel<<<1024, 256, 0, stream>>>(x_id, P, UreT, H17, C17, H15, C15,
                                          W_out, b_out, out, (1 << 16) - 1);
  fusedb_kernel<<<256, 256, 0, stream>>>(x_id, P, UreT, H15, C15, H13, C13,
                                         W_out, b_out, out, (1 << 14) - 1);
  fusedb_kernel<<<64, 256, 0, stream>>>(x_id, P, UreT, H13, C13, H11, C11,
                                        W_out, b_out, out, (1 << 12) - 1);
  fusedb_kernel<<<16, 256, 0, stream>>>(x_id, P, UreT, H11, C11, H9, C9,
                                        W_out, b_out, out, (1 << 10) - 1);
  fusedb_kernel<<<4, 256, 0, stream>>>(x_id, P, UreT, H9, C9, H7, C7,
                                       W_out, b_out, out, (1 << 8) - 1);
  fusedb_kernel<<<1, 256, 0, stream>>>(x_id, P, UreT, H7, C7, H5, C5,
                                       W_out, b_out, out, (1 << 6) - 1);
  // levels 4..0 (L5 children sit in H5/C5)
  tail_kernel<<<1, 256, 0, stream>>>(x_id, P, UreT, H5, HSc, C5, CSc, W_out, b_out, out);

  (void)in_sizes; (void)n_in; (void)out_size; (void)ws_size;
}

// Round 13
// 810.223 us; speedup vs baseline: 1.2189x; 1.2189x over previous
//
#include <hip/hip_runtime.h>
#include <cstdint>

typedef _Float16 f16_t;
typedef __attribute__((ext_vector_type(8))) _Float16 f16x8;
typedef __attribute__((ext_vector_type(4))) _Float16 f16x4;
typedef __attribute__((ext_vector_type(4))) float f32x4;

#define HP      160      // padded H (150 -> 160): h/c row stride, U K-dim
#define NCOL    640      // 160 j x 4 gates (P is [v][j][g] interleaved)
#define KXP     320      // padded X_SIZE (300 -> 320)
#define NNODES  524287
#define LEAF_S  262143
#define LEAF_M  262144
#define NVOCAB  50000
#define AST     168      // A_sh stride (f16): 16B-aligned, 2-way-bank-free

__device__ __forceinline__ float frcp(float x) { return __builtin_amdgcn_rcpf(x); }
__device__ __forceinline__ float sigf(float x) { return frcp(1.0f + __expf(-x)); }
__device__ __forceinline__ float tanhf_(float x) {
  return 1.0f - 2.0f * frcp(1.0f + __expf(2.0f * x));
}
__device__ __forceinline__ f16x8 zero8() {
  f16x8 z;
#pragma unroll
  for (int i = 0; i < 8; ++i) z[i] = (_Float16)0.0f;
  return z;
}
__device__ __forceinline__ f32x4 zero4() {
  f32x4 z;
#pragma unroll
  for (int i = 0; i < 4; ++i) z[i] = 0.0f;
  return z;
}

// WreT[colIdx][k], colIdx = j*4+g (interleaved, matches P);
// UreT[col][k], col = g*160+j (g-major, matches B staging); bre interleaved.
__global__ void prep_params(const float* __restrict__ W_iou, const float* __restrict__ U_iou,
                            const float* __restrict__ b_iou, const float* __restrict__ W_f,
                            const float* __restrict__ U_f, const float* __restrict__ b_f,
                            f16_t* __restrict__ WreT, f16_t* __restrict__ UreT,
                            float* __restrict__ bre) {
  int idx = blockIdx.x * 256 + threadIdx.x;
  if (idx < NCOL * KXP) {
    int col = idx / KXP, k = idx % KXP;
    int j = col >> 2, g = col & 3;
    float v = 0.0f;
    if (k < 300 && j < 150) v = (g < 3) ? W_iou[k * 450 + g * 150 + j] : W_f[k * 150 + j];
    WreT[idx] = (f16_t)v;
  } else if (idx < NCOL * KXP + NCOL * HP) {
    int i2 = idx - NCOL * KXP;
    int col = i2 / HP, k = i2 % HP;
    int g = col / 160, j = col % 160;
    float v = 0.0f;
    if (k < 150 && j < 150) v = (g < 3) ? U_iou[k * 450 + g * 150 + j] : U_f[k * 150 + j];
    UreT[i2] = (f16_t)v;
  } else if (idx < NCOL * KXP + NCOL * HP + NCOL) {
    int col = idx - (NCOL * KXP + NCOL * HP);
    int j = col >> 2, g = col & 3;
    bre[col] = (j < 150) ? ((g < 3) ? b_iou[g * 150 + j] : b_f[j]) : 0.0f;
  }
}

// P[v][j][g] = emb @ W + b, fp16, 50000 x 640 (interleaved cols).
__global__ __launch_bounds__(256) void gemm_p(const float* __restrict__ emb,
                                              const f16_t* __restrict__ WreT,
                                              const float* __restrict__ bre,
                                              f16_t* __restrict__ P) {
  __shared__ __align__(16) f16_t A_sh[64 * 328];
  __shared__ __align__(16) f16_t B_sh[128 * 40];
  const int tid = threadIdx.x;
  const int wid = tid >> 6, lane = tid & 63, l15 = lane & 15, q = lane >> 4;
  const int row0 = blockIdx.x * 64;

#pragma unroll
  for (int i = 0; i < 10; ++i) {
    int ch = tid + 256 * i;
    int r = ch / 40, kc = (ch % 40) * 8;
    int grow = row0 + r;
    f16x8 hv;
    if (grow < NVOCAB && kc + 8 <= 300) {
      float4 a = *(const float4*)&emb[grow * 300 + kc];
      float4 b = *(const float4*)&emb[grow * 300 + kc + 4];
      hv[0] = (_Float16)a.x; hv[1] = (_Float16)a.y; hv[2] = (_Float16)a.z; hv[3] = (_Float16)a.w;
      hv[4] = (_Float16)b.x; hv[5] = (_Float16)b.y; hv[6] = (_Float16)b.z; hv[7] = (_Float16)b.w;
    } else {
#pragma unroll
      for (int e = 0; e < 8; ++e) {
        int k = kc + e;
        float v = (grow < NVOCAB && k < 300) ? emb[grow * 300 + k] : 0.0f;
        hv[e] = (_Float16)v;
      }
    }
    *(f16x8*)&A_sh[r * 328 + kc] = hv;
  }
  __syncthreads();

  for (int bn = 0; bn < 5; ++bn) {
    const int col0 = bn * 128;
    f32x4 acc[8];
#pragma unroll
    for (int t = 0; t < 8; ++t) acc[t] = zero4();
    for (int kk = 0; kk < KXP; kk += 32) {
#pragma unroll
      for (int i = 0; i < 2; ++i) {
        int ch = tid + 256 * i;
        int cidx = ch >> 2, kc = (ch & 3) * 8;
        *(f16x8*)&B_sh[cidx * 40 + kc] =
            *(const f16x8*)&WreT[(col0 + cidx) * KXP + kk + kc];
      }
      __syncthreads();
      f16x8 af = *(const f16x8*)&A_sh[(16 * wid + l15) * 328 + kk + q * 8];
#pragma unroll
      for (int t = 0; t < 8; ++t) {
        f16x8 bfr = *(const f16x8*)&B_sh[(t * 16 + l15) * 40 + q * 8];
        acc[t] = __builtin_amdgcn_mfma_f32_16x16x32_f16(af, bfr, acc[t], 0, 0, 0);
      }
      __syncthreads();
    }
#pragma unroll
    for (int t = 0; t < 8; ++t) {
      int col = col0 + t * 16 + l15;
      float bias = bre[col];
#pragma unroll
      for (int r2 = 0; r2 < 4; ++r2) {
        int row = row0 + 16 * wid + q * 4 + r2;
        if (row < NVOCAB) P[(long)row * NCOL + col] = (f16_t)(acc[t][r2] + bias);
      }
    }
  }
}

// Merged leaf kernel (harness-verified in round 10): per vocab row, compute
// Hleaf/Cleaf AND Oleaf in one pass over P. 16 lanes/row, 16 rows/block.
__global__ void leafhco_kernel(const f16_t* __restrict__ P, const float* __restrict__ W_out,
                               const float* __restrict__ b_out, f16_t* __restrict__ Hleaf,
                               f16_t* __restrict__ Cleaf, float* __restrict__ Oleaf) {
  const int tid = threadIdx.x;
  const int row = blockIdx.x * 16 + (tid >> 4), l = tid & 15;
  const f16_t* Pr = P + (long)row * NCOL;
  float oacc[5] = {0, 0, 0, 0, 0};
#pragma unroll
  for (int jj = 0; jj < 10; ++jj) {
    int j = jj * 16 + l;
    f16x4 pp = *(const f16x4*)&Pr[j * 4];
    float iv = (float)pp[0], ov = (float)pp[1], uv = (float)pp[2];
    float cl = sigf(iv) * tanhf_(uv);     // pads (j>=150): P cols exactly 0 -> cl=hl=0
    float hl = sigf(ov) * tanhf_(cl);
    Hleaf[(long)row * HP + j] = (f16_t)hl;
    Cleaf[(long)row * HP + j] = (f16_t)cl;
    int wbase = (j < 150) ? j * 5 : 0;    // hl==0 on pads
#pragma unroll
    for (int m = 0; m < 5; ++m) oacc[m] += hl * W_out[wbase + m];
  }
#pragma unroll
  for (int m = 0; m < 5; ++m) {
    float vv = oacc[m];
    vv += __shfl_xor(vv, 1);
    vv += __shfl_xor(vv, 2);
    vv += __shfl_xor(vv, 4);
    vv += __shfl_xor(vv, 8);
    if (l == 0) Oleaf[(long)row * 8 + m] = vv + b_out[m];
  }
}

// LEVEL 17, big-M tile: 128 leaves -> 64 parents per block (2048 blocks).
// Also writes the LEAF output rows (its 128 leaves) from Oleaf — leafout
// folded in (harness-verified in round 10).
__global__ __launch_bounds__(256, 3) void level17b_kernel(
    const int* __restrict__ x_id, const f16_t* __restrict__ P,
    const f16_t* __restrict__ UreT, const f16_t* __restrict__ Hleaf,
    const f16_t* __restrict__ Cleaf, const float* __restrict__ Oleaf,
    f16_t* __restrict__ Hout, f16_t* __restrict__ Cout,
    const float* __restrict__ W_out, const float* __restrict__ b_out,
    float* __restrict__ out) {
  __shared__ __align__(16) f16_t A_sh[128 * AST];
  __shared__ __align__(16) f16_t B_sh[128 * 40];
  const int tid = threadIdx.x;
  const int wid = tid >> 6, lane = tid & 63, l15 = lane & 15, q = lane >> 4;
  const int p0 = blockIdx.x * 64;
  const int s1 = (1 << 17) - 1;                  // 131071
  const long childbase = 2L * s1 + 1 + 2 * p0;   // first child (leaf) node id

#pragma unroll
  for (int i = 0; i < 10; ++i) {
    int ch = tid + 256 * i;
    int r = ch / 20, kc = (ch % 20) * 8;
    int xv = x_id[childbase + r];
    *(f16x8*)&A_sh[r * AST + kc] = *(const f16x8*)&Hleaf[(long)xv * HP + kc];
  }
  __syncthreads();

  int xvp[2][2], xvl[2][2], xvr[2][2];
#pragma unroll
  for (int mt = 0; mt < 2; ++mt)
#pragma unroll
    for (int rr = 0; rr < 2; ++rr) {
      int pl = 16 * wid + 8 * mt + 2 * q + rr;   // 0..63
      xvp[mt][rr] = x_id[(long)s1 + p0 + pl];
      xvl[mt][rr] = x_id[childbase + 2 * pl];
      xvr[mt][rr] = x_id[childbase + 2 * pl + 1];
    }
  float oacc[2][2][5] = {};

  for (int jt = 0; jt < 5; ++jt) {
    const int j0 = jt * 32;
    f32x4 acc[2][4][2];
#pragma unroll
    for (int mt = 0; mt < 2; ++mt)
#pragma unroll
      for (int g = 0; g < 4; ++g)
#pragma unroll
        for (int jh = 0; jh < 2; ++jh) acc[mt][g][jh] = zero4();

    for (int kk = 0; kk < HP; kk += 32) {
#pragma unroll
      for (int i = 0; i < 2; ++i) {
        int ch = tid + 256 * i;
        int cidx = ch >> 2, kc = (ch & 3) * 8;
        int g = cidx >> 5, jj = cidx & 31;
        int col = g * HP + j0 + jj;
        *(f16x8*)&B_sh[cidx * 40 + kc] = *(const f16x8*)&UreT[col * HP + kk + kc];
      }
      __syncthreads();
      f16x8 af0 = *(const f16x8*)&A_sh[(32 * wid + l15) * AST + kk + q * 8];
      f16x8 af1 = *(const f16x8*)&A_sh[(32 * wid + 16 + l15) * AST + kk + q * 8];
#pragma unroll
      for (int g = 0; g < 4; ++g)
#pragma unroll
        for (int jh = 0; jh < 2; ++jh) {
          f16x8 bfr = *(const f16x8*)&B_sh[(g * 32 + jh * 16 + l15) * 40 + q * 8];
          acc[0][g][jh] = __builtin_amdgcn_mfma_f32_16x16x32_f16(af0, bfr, acc[0][g][jh], 0, 0, 0);
          acc[1][g][jh] = __builtin_amdgcn_mfma_f32_16x16x32_f16(af1, bfr, acc[1][g][jh], 0, 0, 0);
        }
      __syncthreads();
    }

#pragma unroll
    for (int mt = 0; mt < 2; ++mt)
#pragma unroll
      for (int rr = 0; rr < 2; ++rr) {
        const int r = rr * 2;
        const int pl = 16 * wid + 8 * mt + 2 * q + rr;  // local parent 0..63
        const f16_t* Prp = P + (long)xvp[mt][rr] * NCOL;
#pragma unroll
        for (int jh = 0; jh < 2; ++jh) {
          const int j = j0 + jh * 16 + l15;
          f16x4 pp = *(const f16x4*)&Prp[j * 4];
          float ipre = (float)pp[0] + acc[mt][0][jh][r] + acc[mt][0][jh][r + 1];
          float opre = (float)pp[1] + acc[mt][1][jh][r] + acc[mt][1][jh][r + 1];
          float upre = (float)pp[2] + acc[mt][2][jh][r] + acc[mt][2][jh][r + 1];
          float pf   = (float)pp[3];
          float fl = sigf(pf + acc[mt][3][jh][r]);
          float fr = sigf(pf + acc[mt][3][jh][r + 1]);
          float clv = (float)Cleaf[(long)xvl[mt][rr] * HP + j];
          float crv = (float)Cleaf[(long)xvr[mt][rr] * HP + j];
          float cn = sigf(ipre) * tanhf_(upre) + fl * clv + fr * crv;
          float hn = sigf(opre) * tanhf_(cn);
          Hout[(long)(p0 + pl) * HP + j] = (f16_t)hn;   // pads stay exactly 0
          Cout[(long)(p0 + pl) * HP + j] = (f16_t)cn;
          int wbase = (j < 150) ? j * 5 : 0;            // hn==0 on pads
#pragma unroll
          for (int m = 0; m < 5; ++m) oacc[mt][rr][m] += hn * W_out[wbase + m];
        }
      }
  }

#pragma unroll
  for (int mt = 0; mt < 2; ++mt)
#pragma unroll
    for (int rr = 0; rr < 2; ++rr) {
      int pl = 16 * wid + 8 * mt + 2 * q + rr;
#pragma unroll
      for (int m = 0; m < 5; ++m) {
        float v = oacc[mt][rr][m];
        v += __shfl_xor(v, 1);
        v += __shfl_xor(v, 2);
        v += __shfl_xor(v, 4);
        v += __shfl_xor(v, 8);
        if (l15 == 0) out[((long)s1 + p0 + pl) * 5 + m] = v + b_out[m];
      }
    }

  // ---- folded leafout: this block's 128 leaves ----
  if (tid < 128) {
    long leaf = childbase + tid;
    int xv = x_id[leaf];
    const float* O = Oleaf + (long)xv * 8;
    float4 o4 = *(const float4*)O;
    float o5 = O[4];
    long base = leaf * 5;
    out[base + 0] = o4.x; out[base + 1] = o4.y; out[base + 2] = o4.z;
    out[base + 3] = o4.w; out[base + 4] = o5;
  }
}

// Two fused levels per block (round-0/3/9 proven structure): 64 children ->
// 32 parents (level s1, h->A2_sh c->C_sh) -> 16 grandparents.
template <bool LEAF>
__global__ __launch_bounds__(256, 3) void fused_kernel(
    const int* __restrict__ x_id, const f16_t* __restrict__ P,
    const f16_t* __restrict__ UreT, const f16_t* __restrict__ Hc,
    const f16_t* __restrict__ Cc, f16_t* __restrict__ Hout,
    f16_t* __restrict__ Cout, const float* __restrict__ W_out,
    const float* __restrict__ b_out, float* __restrict__ out, int s1, int M1) {
  __shared__ __align__(16) f16_t A_sh[64 * AST];
  __shared__ __align__(16) f16_t A2_sh[32 * AST];
  __shared__ __align__(16) f16_t B_sh[128 * 40];
  __shared__ f16_t C_sh[32 * 160];
  const int tid = threadIdx.x;
  const int wid = tid >> 6, lane = tid & 63, l15 = lane & 15, q = lane >> 4;
  const int p0 = blockIdx.x * 32;
  const long childbase = 2L * s1 + 1 + 2 * p0;

#pragma unroll
  for (int i = 0; i < 5; ++i) {
    int ch = tid + 256 * i;
    int r = ch / 20, kc = (ch % 20) * 8;
    f16x8 v;
    if (LEAF) {
      int xv = x_id[childbase + r];
      v = *(const f16x8*)&Hc[(long)xv * HP + kc];
    } else {
      v = *(const f16x8*)&Hc[(long)(2 * p0 + r) * HP + kc];
    }
    *(f16x8*)&A_sh[r * AST + kc] = v;
  }
  __syncthreads();

  int xvp[2], xvl[2], xvr[2];
#pragma unroll
  for (int rr = 0; rr < 2; ++rr) {
    int pl = 8 * wid + 2 * q + rr;
    long pn = (long)s1 + p0 + pl;
    xvp[rr] = x_id[pn];
    if (LEAF) {
      xvl[rr] = x_id[childbase + 2 * pl];
      xvr[rr] = x_id[childbase + 2 * pl + 1];
    }
  }
  float oacc1[2][5] = {};

  for (int jt = 0; jt < 5; ++jt) {
    const int j0 = jt * 32;
    f32x4 acc[4][2];
#pragma unroll
    for (int g = 0; g < 4; ++g)
#pragma unroll
      for (int jh = 0; jh < 2; ++jh) acc[g][jh] = zero4();

    for (int kk = 0; kk < HP; kk += 32) {
#pragma unroll
      for (int i = 0; i < 2; ++i) {
        int ch = tid + 256 * i;
        int cidx = ch >> 2, kc = (ch & 3) * 8;
        int g = cidx >> 5, jj = cidx & 31;
        int col = g * HP + j0 + jj;
        *(f16x8*)&B_sh[cidx * 40 + kc] = *(const f16x8*)&UreT[col * HP + kk + kc];
      }
      __syncthreads();
      f16x8 af = *(const f16x8*)&A_sh[(16 * wid + l15) * AST + kk + q * 8];
#pragma unroll
      for (int g = 0; g < 4; ++g)
#pragma unroll
        for (int jh = 0; jh < 2; ++jh) {
          f16x8 bfr = *(const f16x8*)&B_sh[(g * 32 + jh * 16 + l15) * 40 + q * 8];
          acc[g][jh] = __builtin_amdgcn_mfma_f32_16x16x32_f16(af, bfr, acc[g][jh], 0, 0, 0);
        }
      __syncthreads();
    }

#pragma unroll
    for (int rr = 0; rr < 2; ++rr) {
      const int r = rr * 2;
      const int lr0 = 16 * wid + q * 4 + r;
      const int pl = lr0 >> 1;
      const f16_t* Prp = P + (long)xvp[rr] * NCOL;
#pragma unroll
      for (int jh = 0; jh < 2; ++jh) {
        const int j = j0 + jh * 16 + l15;
        f16x4 pp = *(const f16x4*)&Prp[j * 4];
        float ipre = (float)pp[0] + acc[0][jh][r] + acc[0][jh][r + 1];
        float opre = (float)pp[1] + acc[1][jh][r] + acc[1][jh][r + 1];
        float upre = (float)pp[2] + acc[2][jh][r] + acc[2][jh][r + 1];
        float pf   = (float)pp[3];
        float fl = sigf(pf + acc[3][jh][r]);
        float fr = sigf(pf + acc[3][jh][r + 1]);
        float clv, crv;
        if (LEAF) {
          clv = (float)Cc[(long)xvl[rr] * HP + j];
          crv = (float)Cc[(long)xvr[rr] * HP + j];
        } else {
          clv = (float)Cc[(long)(2 * p0 + lr0) * HP + j];
          crv = (float)Cc[(long)(2 * p0 + lr0 + 1) * HP + j];
        }
        float cn = sigf(ipre) * tanhf_(upre) + fl * clv + fr * crv;
        float hn = sigf(opre) * tanhf_(cn);
        A2_sh[pl * AST + j] = (f16_t)hn;
        C_sh[pl * 160 + j] = (f16_t)cn;
        int wbase = (j < 150) ? j * 5 : 0;
#pragma unroll
        for (int m = 0; m < 5; ++m) oacc1[rr][m] += hn * W_out[wbase + m];
      }
    }
  }

#pragma unroll
  for (int rr = 0; rr < 2; ++rr) {
    int pl = 8 * wid + 2 * q + rr;
#pragma unroll
    for (int m = 0; m < 5; ++m) {
      float v = oacc1[rr][m];
      v += __shfl_xor(v, 1);
      v += __shfl_xor(v, 2);
      v += __shfl_xor(v, 4);
      v += __shfl_xor(v, 8);
      if (l15 == 0) out[((long)s1 + p0 + pl) * 5 + m] = v + b_out[m];
    }
  }

  const int s2 = (s1 - 1) >> 1;
  const int p02 = p0 >> 1;
  const bool act2 = (wid < 2);
  int xvp2[2];
#pragma unroll
  for (int rr = 0; rr < 2; ++rr) {
    int pl = 8 * wid + 2 * q + rr;
    long pn = (long)s2 + p02 + (act2 ? pl : 0);
    xvp2[rr] = x_id[pn];
  }
  float oacc2[2][5] = {};

  for (int jt = 0; jt < 5; ++jt) {
    const int j0 = jt * 32;
    f32x4 acc[4][2];
#pragma unroll
    for (int g = 0; g < 4; ++g)
#pragma unroll
      for (int jh = 0; jh < 2; ++jh) acc[g][jh] = zero4();

    for (int kk = 0; kk < HP; kk += 32) {
#pragma unroll
      for (int i = 0; i < 2; ++i) {
        int ch = tid + 256 * i;
        int cidx = ch >> 2, kc = (ch & 3) * 8;
        int g = cidx >> 5, jj = cidx & 31;
        int col = g * HP + j0 + jj;
        *(f16x8*)&B_sh[cidx * 40 + kc] = *(const f16x8*)&UreT[col * HP + kk + kc];
      }
      __syncthreads();
      if (act2) {
        f16x8 af = *(const f16x8*)&A2_sh[(16 * wid + l15) * AST + kk + q * 8];
#pragma unroll
        for (int g = 0; g < 4; ++g)
#pragma unroll
          for (int jh = 0; jh < 2; ++jh) {
            f16x8 bfr = *(const f16x8*)&B_sh[(g * 32 + jh * 16 + l15) * 40 + q * 8];
            acc[g][jh] = __builtin_amdgcn_mfma_f32_16x16x32_f16(af, bfr, acc[g][jh], 0, 0, 0);
          }
      }
      __syncthreads();
    }

    if (act2) {
#pragma unroll
      for (int rr = 0; rr < 2; ++rr) {
        const int r = rr * 2;
        const int lr0 = 16 * wid + q * 4 + r;
        const int pl = lr0 >> 1;
        const f16_t* Prp = P + (long)xvp2[rr] * NCOL;
#pragma unroll
        for (int jh = 0; jh < 2; ++jh) {
          const int j = j0 + jh * 16 + l15;
          f16x4 pp = *(const f16x4*)&Prp[j * 4];
          float ipre = (float)pp[0] + acc[0][jh][r] + acc[0][jh][r + 1];
          float opre = (float)pp[1] + acc[1][jh][r] + acc[1][jh][r + 1];
          float upre = (float)pp[2] + acc[2][jh][r] + acc[2][jh][r + 1];
          float pf   = (float)pp[3];
          float fl = sigf(pf + acc[3][jh][r]);
          float fr = sigf(pf + acc[3][jh][r + 1]);
          float clv = (float)C_sh[lr0 * 160 + j];
          float crv = (float)C_sh[(lr0 + 1) * 160 + j];
          float cn = sigf(ipre) * tanhf_(upre) + fl * clv + fr * crv;
          float hn = sigf(opre) * tanhf_(cn);
          Hout[(long)(p02 + pl) * HP + j] = (f16_t)hn;
          Cout[(long)(p02 + pl) * HP + j] = (f16_t)cn;
          int wbase = (j < 150) ? j * 5 : 0;
#pragma unroll
          for (int m = 0; m < 5; ++m) oacc2[rr][m] += hn * W_out[wbase + m];
        }
      }
    }
  }

  if (act2) {
#pragma unroll
    for (int rr = 0; rr < 2; ++rr) {
      int pl = 8 * wid + 2 * q + rr;
#pragma unroll
      for (int m = 0; m < 5; ++m) {
        float v = oacc2[rr][m];
        v += __shfl_xor(v, 1);
        v += __shfl_xor(v, 2);
        v += __shfl_xor(v, 4);
        v += __shfl_xor(v, 8);
        if (l15 == 0) out[((long)s2 + p02 + pl) * 5 + m] = v + b_out[m];
      }
    }
  }
}

// ---------------- single-level tile for the tail (unchanged, proven) -------
__device__ __forceinline__ void level_tile(
    const int* __restrict__ x_id, const f16_t* __restrict__ P,
    const f16_t* __restrict__ UreT, const f16_t* __restrict__ h_child,
    const f16_t* __restrict__ c_child, f16_t* __restrict__ h_par,
    f16_t* __restrict__ c_par, const float* Wo, const float* __restrict__ b_out,
    float* __restrict__ out, int s, int M, int p0, f16_t* A_sh, f16_t* B_sh) {
  const int tid = threadIdx.x;
  const int wid = tid >> 6, lane = tid & 63, l15 = lane & 15, q = lane >> 4;
  int rowsValid = 2 * M - 2 * p0;
  if (rowsValid > 64) rowsValid = 64;

#pragma unroll
  for (int i = 0; i < 5; ++i) {
    int ch = tid + 256 * i;
    int r = ch / 20, kc = (ch % 20) * 8;
    f16x8 v;
    if (r < rowsValid) v = *(const f16x8*)&h_child[(long)(2 * p0 + r) * HP + kc];
    else v = zero8();
    *(f16x8*)&A_sh[r * 184 + kc] = v;
  }
  __syncthreads();

  int xvp[2]; long pnode[2]; int plg[2]; bool valid[2]; int lr0v[2];
#pragma unroll
  for (int rr = 0; rr < 2; ++rr) {
    int lr0 = 16 * wid + q * 4 + rr * 2;
    int pl = lr0 >> 1;
    valid[rr] = (p0 + pl) < M;
    long pn = (long)s + p0 + (valid[rr] ? pl : 0);
    pnode[rr] = pn; plg[rr] = p0 + pl; lr0v[rr] = lr0;
    xvp[rr] = x_id[pn];
  }

  float oacc[2][5];
#pragma unroll
  for (int rr = 0; rr < 2; ++rr)
#pragma unroll
    for (int m = 0; m < 5; ++m) oacc[rr][m] = 0.0f;

  for (int jt = 0; jt < 5; ++jt) {
    const int j0 = jt * 32;
    f32x4 acc[4][2];
#pragma unroll
    for (int g = 0; g < 4; ++g)
#pragma unroll
      for (int jh = 0; jh < 2; ++jh) acc[g][jh] = zero4();

    for (int kk = 0; kk < HP; kk += 32) {
#pragma unroll
      for (int i = 0; i < 2; ++i) {
        int ch = tid + 256 * i;
        int cidx = ch >> 2, kc = (ch & 3) * 8;
        int g = cidx >> 5, jj = cidx & 31;
        int col = g * HP + j0 + jj;
        *(f16x8*)&B_sh[cidx * 40 + kc] = *(const f16x8*)&UreT[col * HP + kk + kc];
      }
      __syncthreads();
      f16x8 af = *(const f16x8*)&A_sh[(16 * wid + l15) * 184 + kk + q * 8];
#pragma unroll
      for (int g = 0; g < 4; ++g)
#pragma unroll
        for (int jh = 0; jh < 2; ++jh) {
          f16x8 bfr = *(const f16x8*)&B_sh[(g * 32 + jh * 16 + l15) * 40 + q * 8];
          acc[g][jh] = __builtin_amdgcn_mfma_f32_16x16x32_f16(af, bfr, acc[g][jh], 0, 0, 0);
        }
      __syncthreads();
    }

#pragma unroll
    for (int rr = 0; rr < 2; ++rr) {
      const int r = rr * 2;
      const f16_t* Prp = P + (long)xvp[rr] * NCOL;
#pragma unroll
      for (int jh = 0; jh < 2; ++jh) {
        const int j = j0 + jh * 16 + l15;
        f16x4 pp = *(const f16x4*)&Prp[j * 4];
        float ipre = (float)pp[0] + acc[0][jh][r] + acc[0][jh][r + 1];
        float opre = (float)pp[1] + acc[1][jh][r] + acc[1][jh][r + 1];
        float upre = (float)pp[2] + acc[2][jh][r] + acc[2][jh][r + 1];
        float pf   = (float)pp[3];
        float fl = sigf(pf + acc[3][jh][r]);
        float fr = sigf(pf + acc[3][jh][r + 1]);
        float clv = valid[rr] ? (float)c_child[(long)(2 * p0 + lr0v[rr]) * HP + j] : 0.0f;
        float crv = valid[rr] ? (float)c_child[(long)(2 * p0 + lr0v[rr] + 1) * HP + j] : 0.0f;
        float cn = sigf(ipre) * tanhf_(upre) + fl * clv + fr * crv;
        float hn = sigf(opre) * tanhf_(cn);
        if (valid[rr]) {
          h_par[(long)plg[rr] * HP + j] = (f16_t)hn;
          c_par[(long)plg[rr] * HP + j] = (f16_t)cn;
        }
#pragma unroll
        for (int m = 0; m < 5; ++m) oacc[rr][m] += hn * Wo[j * 5 + m];
      }
    }
  }

#pragma unroll
  for (int rr = 0; rr < 2; ++rr) {
#pragma unroll
    for (int m = 0; m < 5; ++m) {
      float v = oacc[rr][m];
      v += __shfl_xor(v, 1);
      v += __shfl_xor(v, 2);
      v += __shfl_xor(v, 4);
      v += __shfl_xor(v, 8);
      if (l15 == 0 && valid[rr]) out[pnode[rr] * 5 + m] = v + b_out[m];
    }
  }
}

// Levels 4..0 (children: L5 in HA/CA): one block, barriers between levels.
__global__ __launch_bounds__(256, 4) void tail_kernel(
    const int* __restrict__ x_id, const f16_t* __restrict__ P,
    const f16_t* __restrict__ UreT, f16_t* __restrict__ HA, f16_t* __restrict__ HB,
    f16_t* __restrict__ CA, f16_t* __restrict__ CB, const float* __restrict__ W_out,
    const float* __restrict__ b_out, float* __restrict__ out) {
  __shared__ __align__(16) f16_t A_sh[64 * 184];
  __shared__ __align__(16) f16_t B_sh[128 * 40];
  __shared__ float Wo[800];
  for (int i = threadIdx.x; i < 800; i += 256) Wo[i] = (i < 750) ? W_out[i] : 0.0f;
  for (int lvl = 4; lvl >= 0; --lvl) {
    int s = (1 << lvl) - 1, M = 1 << lvl;
    const f16_t* hc = ((lvl + 1) & 1) ? HA : HB;
    const f16_t* cc = ((lvl + 1) & 1) ? CA : CB;
    f16_t* hp = (lvl & 1) ? HA : HB;
    f16_t* cp = (lvl & 1) ? CA : CB;
    level_tile(x_id, P, UreT, hc, cc, hp, cp, Wo, b_out, out, s, M, 0, A_sh, B_sh);
    __syncthreads();
  }
}

extern "C" void kernel_launch(void* const* d_in, const int* in_sizes, int n_in,
                              void* d_out, int out_size, void* d_ws, size_t ws_size,
                              hipStream_t stream) {
  const int* x_id   = (const int*)d_in[0];
  const float* emb  = (const float*)d_in[1];
  const float* W_iou = (const float*)d_in[2];
  const float* U_iou = (const float*)d_in[3];
  const float* b_iou = (const float*)d_in[4];
  const float* W_f   = (const float*)d_in[5];
  const float* U_f   = (const float*)d_in[6];
  const float* b_f   = (const float*)d_in[7];
  const float* W_out = (const float*)d_in[8];
  const float* b_out = (const float*)d_in[9];
  float* out = (float*)d_out;
  char* ws = (char*)d_ws;

  // workspace carve (bytes), peak 182,103,040 == budget (Oleaf exact fit;
  // round-10-verified layout). All reuses stream-ordered.
  f16_t* WreT  = (f16_t*)(ws + 0);              // 409,600
  f16_t* UreT  = (f16_t*)(ws + 409600);         // 204,800
  float* bre   = (float*)(ws + 614400);         // 2,560
  f16_t* P     = (f16_t*)(ws + 616960);         // 64,000,000 (persistent)
  f16_t* Hleaf = (f16_t*)(ws + 64616960);       // 16,000,000 (dead after L17)
  f16_t* Cleaf = (f16_t*)(ws + 80616960);       // 16,000,000 (dead after L17)
  f16_t* H17   = (f16_t*)(ws + 96616960);       // 41,943,040 (131072 rows)
  f16_t* C17   = (f16_t*)(ws + 138560000);      // 41,943,040 -> ends 180,503,040
  float* Oleaf = (float*)(ws + 180503040);      // 1,600,000 -> ends 182,103,040
  f16_t* H15 = (f16_t*)(ws + 64616960);         // 10,485,760 (32768 rows) over Hleaf
  f16_t* C15 = (f16_t*)(ws + 75102720);         // 10,485,760
  f16_t* H13 = (f16_t*)(ws + 96616960);         //  2,621,440 (8192 rows) over H17
  f16_t* C13 = (f16_t*)(ws + 99238400);         //  2,621,440
  f16_t* H11 = (f16_t*)(ws + 64616960);         //    655,360 (2048 rows) over H15
  f16_t* C11 = (f16_t*)(ws + 65272320);         //    655,360
  f16_t* H9  = (f16_t*)(ws + 96616960);         //    163,840 (512 rows) over H13
  f16_t* C9  = (f16_t*)(ws + 96780800);         //    163,840
  f16_t* H7  = (f16_t*)(ws + 64616960);         //     40,960 (128 rows) over H11
  f16_t* C7  = (f16_t*)(ws + 64657920);         //     40,960
  f16_t* H5  = (f16_t*)(ws + 96616960);         //     10,240 (32 rows) over H9
  f16_t* C5  = (f16_t*)(ws + 96627200);         //     10,240
  f16_t* HSc = (f16_t*)(ws + 64616960);         // tail scratch (over H7, dead)
  f16_t* CSc = (f16_t*)(ws + 64627200);         // tail scratch

  prep_params<<<1203, 256, 0, stream>>>(W_iou, U_iou, b_iou, W_f, U_f, b_f, WreT, UreT, bre);
  gemm_p<<<782, 256, 0, stream>>>(emb, WreT, bre, P);
  leafhco_kernel<<<3125, 256, 0, stream>>>(P, W_out, b_out, Hleaf, Cleaf, Oleaf);

  // level 17: big-M tile + folded leaf-output gather
  level17b_kernel<<<2048, 256, 0, stream>>>(x_id, P, UreT, Hleaf, Cleaf, Oleaf,
                                            H17, C17, W_out, b_out, out);
  // fused pairs (round-9 proven):
  fused_kernel<false><<<2048, 256, 0, stream>>>(x_id, P, UreT, H17, C17, H15, C15,
                                                W_out, b_out, out, (1 << 16) - 1, 1 << 16);
  fused_kernel<false><<<512, 256, 0, stream>>>(x_id, P, UreT, H15, C15, H13, C13,
                                               W_out, b_out, out, (1 << 14) - 1, 1 << 14);
  fused_kernel<false><<<128, 256, 0, stream>>>(x_id, P, UreT, H13, C13, H11, C11,
                                               W_out, b_out, out, (1 << 12) - 1, 1 << 12);
  fused_kernel<false><<<32, 256, 0, stream>>>(x_id, P, UreT, H11, C11, H9, C9,
                                              W_out, b_out, out, (1 << 10) - 1, 1 << 10);
  fused_kernel<false><<<8, 256, 0, stream>>>(x_id, P, UreT, H9, C9, H7, C7,
                                             W_out, b_out, out, (1 << 8) - 1, 1 << 8);
  fused_kernel<false><<<2, 256, 0, stream>>>(x_id, P, UreT, H7, C7, H5, C5,
                                             W_out, b_out, out, (1 << 6) - 1, 1 << 6);
  // levels 4..0 (L5 children sit in H5/C5)
  tail_kernel<<<1, 256, 0, stream>>>(x_id, P, UreT, H5, HSc, C5, CSc, W_out, b_out, out);

  (void)in_sizes; (void)n_in; (void)out_size; (void)ws_size;
}